// Round 14
// baseline (152.539 us; speedup 1.0000x reference)
//
#include <hip/hip_runtime.h>
#include <cstddef>

#define HH 512
#define WW 512
#define BB 8
#define T  32

// ws layout (floats):
//   [0..72)      keff_edge  (3*3)*8ch
//   [72..193)    Keff11     11*11
//   [256..1280)  F-bank (grad filters): 4 tiles x 64 lanes x 8 bf16
//   [1280..4096) KT-bank (kappa Toeplitz): 11 b x 64 lanes x 8 bf16
//                KT_b[m=lane&15][k=(lane>>4)*8+j] = Keff11[k-m-3][b] if 0<=k-m-3<11
#define F0    256
#define KT0   1280
#define WS_NEEDED_BYTES ((size_t)4096 * 4)

typedef __attribute__((ext_vector_type(8))) short short8;
typedef __attribute__((ext_vector_type(4))) float float4v;

__device__ inline unsigned short f2bf(float f) {   // fp32 -> bf16 RNE
  unsigned u = __builtin_bit_cast(unsigned, f);
  unsigned r = (u + 0x7FFFu + ((u >> 16) & 1u)) >> 16;
  return (unsigned short)r;
}
__device__ inline float bf2f(unsigned short h) {
  unsigned u = ((unsigned)h) << 16;
  return __builtin_bit_cast(float, u);
}

__global__ __launch_bounds__(256) void precompute_kernels(
    const float* __restrict__ kd,   // (3,3,1,8)
    const float* __restrict__ kp,   // (1,1,8,8)
    const float* __restrict__ k0,   // (5,5,1,8)
    const float* __restrict__ k1,   // (5,5,8,8)
    const float* __restrict__ k2,   // (3,3,8,16)
    const float* __restrict__ kx,   // (3,3,1,32)
    const float* __restrict__ ky,   // (3,3,1,32)
    float* __restrict__ ws) {
  __shared__ float k9[648];
  __shared__ float k2s[72];
  __shared__ float kef[121];
  const int tid = threadIdx.x;

  for (int idx = tid; idx < 72; idx += 256) {
    int c = idx & 7, pq = idx >> 3;
    float s = 0.f;
    for (int c0 = 0; c0 < 8; ++c0) s = fmaf(kd[pq * 8 + c0], kp[c0 * 8 + c], s);
    ws[idx] = s;
  }
  for (int idx = tid; idx < 72; idx += 256) {
    int c1 = idx & 7, tv = idx >> 3;
    float s = 0.f;
    for (int c2 = 0; c2 < 16; ++c2) s += k2[(tv * 8 + c1) * 16 + c2];
    k2s[idx] = s;
  }
  for (int idx = tid; idx < 648; idx += 256) {
    int c1 = idx & 7;
    int ab = idx >> 3;
    int a = ab / 9, b = ab % 9;
    float s = 0.f;
    int plo = a > 4 ? a - 4 : 0, phi = a < 4 ? a : 4;
    int qlo = b > 4 ? b - 4 : 0, qhi = b < 4 ? b : 4;
    for (int p = plo; p <= phi; ++p)
      for (int q = qlo; q <= qhi; ++q) {
        int r = a - p, sx = b - q;
        const float* k0p = &k0[(p * 5 + q) * 8];
        const float* k1p = &k1[((r * 5 + sx) * 8) * 8 + c1];
        for (int c0 = 0; c0 < 8; ++c0) s = fmaf(k0p[c0], k1p[c0 * 8], s);
      }
    k9[idx] = s;
  }
  // F-bank (grad filters)
  for (int idx = tid; idx < 2048; idx += 256) {
    int nt = idx >> 9, ln = (idx >> 3) & 63, j = idx & 7;
    int k = (ln >> 4) * 8 + j;
    int n = nt * 16 + (ln & 15);
    float v = 0.f;
    if (k < 9) v = (n < 32) ? kx[k * 32 + n] : ky[k * 32 + (n - 32)];
    ((unsigned short*)ws)[F0 * 2 + idx] = f2bf(v);
  }
  __syncthreads();
  for (int idx = tid; idx < 121; idx += 256) {
    int A = idx / 11, B = idx % 11;
    float s = 0.f;
    int tlo = A > 8 ? A - 8 : 0, thi = A < 2 ? A : 2;
    int vlo = B > 8 ? B - 8 : 0, vhi = B < 2 ? B : 2;
    for (int t = tlo; t <= thi; ++t)
      for (int v = vlo; v <= vhi; ++v) {
        int a = A - t, b = B - v;
        for (int c1 = 0; c1 < 8; ++c1)
          s = fmaf(k9[(a * 9 + b) * 8 + c1], k2s[(t * 3 + v) * 8 + c1], s);
      }
    ws[72 + idx] = s;
    kef[idx] = s;
  }
  __syncthreads();
  // KT-bank: kappa Toeplitz A-frags (bf16)
  for (int idx = tid; idx < 5632; idx += 256) {
    int b = idx >> 9, ln = (idx >> 3) & 63, j = idx & 7;
    int m = ln & 15;
    int k = (ln >> 4) * 8 + j;
    int a = k - m - 3;
    float v = ((unsigned)a < 11u) ? kef[a * 11 + b] : 0.f;
    ((unsigned short*)ws)[KT0 * 2 + idx] = f2bf(v);
  }
}

// ---------------- fused kernel: edges + kappa + grads + smoother + combine --
// R14: (a) suT staged column-per-wave (conflict-free LDS writes, L1-served
// global rereads); (b) se32 dropped, phase 3 reads edge center from sebf ->
// LDS 29504 B -> 5 blocks/CU.
__global__ __launch_bounds__(256) void fused(
    const float* __restrict__ u, const float* __restrict__ img,
    const float* __restrict__ kk, const float* __restrict__ sm,
    const float* __restrict__ ws, float* __restrict__ out) {
  __shared__ unsigned short suT[58 * 72]; // u transposed bf16 [col][row], stride 72
                                          // cols bx-7..bx+50, rows by-10..by+53
  __shared__ float si[36 * 36];           // image tile, r=2 halo, origin (by-2,bx-2)
  __shared__ unsigned short sebf[34 * 36];// edges bf16 (grad MFMA + combine center)
  __shared__ float skp[36 * 37];          // kappa*kk, r=2 halo (smoother input)
  __shared__ float sgx[32 * 32];
  __shared__ float sgy[32 * 32];

  const int bx = blockIdx.x * T, by = blockIdx.y * T, b = blockIdx.z;
  const int tid = threadIdx.x;
  const float* ub = u + (size_t)b * HH * WW;
  const float* ib = img + (size_t)b * HH * WW;

  const int lane = tid & 63;
  const int wv   = tid >> 6;
  const int q    = lane >> 4;
  const int m    = lane & 15;

  // ---- phase 0: stage ----
  // suT: one column per wave-iteration -> lanes write 64 consecutive u16
  // (conflict-free); global column reads are L1-served after first touch.
  for (int idx = tid; idx < 58 * 64; idx += 256) {
    int c = idx >> 6, r = idx & 63;
    int gy = by - 10 + r, gx = bx - 7 + c;
    float v = 0.f;
    if ((unsigned)gy < HH && (unsigned)gx < WW) v = ub[gy * WW + gx];
    suT[c * 72 + r] = f2bf(v);
  }
  for (int idx = tid; idx < 36 * 36; idx += 256) {
    int i = idx / 36, j = idx % 36;
    int gy = by - 2 + i, gx = bx - 2 + j;
    float v = 0.f;
    if ((unsigned)gy < HH && (unsigned)gx < WW) v = ib[gy * WW + gx];
    si[i * 36 + j] = v;
  }
  __syncthreads();

  // ---- phase 1a: edges on 34x34 (strips of 4) ----
  // edge pixel (by-1+i, bx-1+j); window rows by-2+i+p -> si local row i+p.
  for (int idx = tid; idx < 34 * 9; idx += 256) {
    int i = idx / 9, j0 = (idx % 9) * 4;
    float acc[8][4];
    #pragma unroll
    for (int c = 0; c < 8; ++c)
      #pragma unroll
      for (int t = 0; t < 4; ++t) acc[c][t] = 0.f;
    #pragma unroll
    for (int p = 0; p < 3; ++p) {
      float r[6];
      #pragma unroll
      for (int t = 0; t < 6; ++t) r[t] = si[(i + p) * 36 + j0 + t];
      #pragma unroll
      for (int qq = 0; qq < 3; ++qq) {
        float4 w0 = *reinterpret_cast<const float4*>(&ws[(p * 3 + qq) * 8]);
        float4 w1 = *reinterpret_cast<const float4*>(&ws[(p * 3 + qq) * 8 + 4]);
        #pragma unroll
        for (int t = 0; t < 4; ++t) {
          float v = r[qq + t];
          acc[0][t] = fmaf(v, w0.x, acc[0][t]);
          acc[1][t] = fmaf(v, w0.y, acc[1][t]);
          acc[2][t] = fmaf(v, w0.z, acc[2][t]);
          acc[3][t] = fmaf(v, w0.w, acc[3][t]);
          acc[4][t] = fmaf(v, w1.x, acc[4][t]);
          acc[5][t] = fmaf(v, w1.y, acc[5][t]);
          acc[6][t] = fmaf(v, w1.z, acc[6][t]);
          acc[7][t] = fmaf(v, w1.w, acc[7][t]);
        }
      }
    }
    int gy = by - 1 + i;
    #pragma unroll
    for (int t = 0; t < 4; ++t) {
      int j = j0 + t;
      if (j < 34) {
        int gx = bx - 1 + j;
        float val = 0.f;
        if ((unsigned)gy < HH && (unsigned)gx < WW) {
          float e = 0.f;
          #pragma unroll
          for (int c = 0; c < 8; ++c) e += fmaxf(acc[c][t], 0.f);
          val = e / (1.f + e);
        }
        sebf[i * 36 + j] = f2bf(val);
      }
    }
  }

  // ---- phase 1b: kappa via Toeplitz MFMA, 9 subtiles -> skp 36x36 ----
  {
    const unsigned short* KT = ((const unsigned short*)ws) + KT0 * 2;
    for (int s = wv; s < 9; s += 4) {
      int sty = s / 3, stx = s % 3;
      float4v acc = {0.f, 0.f, 0.f, 0.f};
      #pragma unroll
      for (int bb = 0; bb < 11; ++bb) {
        short8 af = *reinterpret_cast<const short8*>(KT + (bb * 64 + lane) * 8);
        // B[k][n] = u[by-2+sty*16+k-8][bx-2+stx*16+n+bb-5]
        short8 bf = *reinterpret_cast<const short8*>(
            &suT[(stx * 16 + m + bb) * 72 + sty * 16 + q * 8]);
        acc = __builtin_amdgcn_mfma_f32_16x16x32_bf16(af, bf, acc, 0, 0, 0);
      }
      #pragma unroll
      for (int i = 0; i < 4; ++i) {
        int rl = sty * 16 + q * 4 + i, cl = stx * 16 + m;
        if (rl < 36 && cl < 36) {
          int yy = by - 2 + rl, xx = bx - 2 + cl;
          float v = 0.f;
          if ((unsigned)yy < HH && (unsigned)xx < WW)
            v = acc[i] * kk[(size_t)yy * WW + xx];
          skp[rl * 37 + cl] = v;
        }
      }
    }
  }
  __syncthreads();

  // ---- phase 2: grads via transposed MFMA (filters=A, pixels=B) ----
  {
    short8 afr[4];
    const unsigned short* F = ((const unsigned short*)ws) + F0 * 2;
    #pragma unroll
    for (int t = 0; t < 4; ++t)
      afr[t] = *reinterpret_cast<const short8*>(F + (t * 64 + lane) * 8);

    #pragma unroll
    for (int h = 0; h < 32; h += 16) {
      const int cl = h + m;                 // pixel col (tile-local)
      unsigned short W[9];
      #pragma unroll
      for (int d = 0; d < 3; ++d) {
        const unsigned short* rp = &sebf[(wv * 8 + d) * 36 + cl];
        W[3 * d + 0] = rp[0]; W[3 * d + 1] = rp[1]; W[3 * d + 2] = rp[2];
      }

      #pragma unroll
      for (int r = 0; r < 8; ++r) {
        short8 bv = (short8)0;
        if (q == 0) {
          #pragma unroll
          for (int j = 0; j < 8; ++j) bv[j] = (short)W[j];
        } else if (q == 1) {
          bv[0] = (short)W[8];
        }

        float4v c0 = {0.f, 0.f, 0.f, 0.f}, c1 = c0, c2 = c0, c3 = c0;
        c0 = __builtin_amdgcn_mfma_f32_16x16x32_bf16(afr[0], bv, c0, 0, 0, 0);
        c1 = __builtin_amdgcn_mfma_f32_16x16x32_bf16(afr[1], bv, c1, 0, 0, 0);
        c2 = __builtin_amdgcn_mfma_f32_16x16x32_bf16(afr[2], bv, c2, 0, 0, 0);
        c3 = __builtin_amdgcn_mfma_f32_16x16x32_bf16(afr[3], bv, c3, 0, 0, 0);

        float rx = 0.f, ry = 0.f;
        #pragma unroll
        for (int i = 0; i < 4; ++i) {
          rx += fmaxf(c0[i], 0.f) + fmaxf(c1[i], 0.f);
          ry += fmaxf(c2[i], 0.f) + fmaxf(c3[i], 0.f);
        }
        rx += __shfl_xor(rx, 16); rx += __shfl_xor(rx, 32);
        ry += __shfl_xor(ry, 16); ry += __shfl_xor(ry, 32);

        if (q == 0) {
          sgx[(wv * 8 + r) * 32 + cl] = rx;
          sgy[(wv * 8 + r) * 32 + cl] = ry;
        }

        if (r < 7) {
          #pragma unroll
          for (int t = 0; t < 6; ++t) W[t] = W[t + 3];
          const unsigned short* rp = &sebf[(wv * 8 + r + 3) * 36 + cl];
          W[6] = rp[0]; W[7] = rp[1]; W[8] = rp[2];
        }
      }
    }
  }
  __syncthreads();

  // ---- phase 3: combine (4-px strip per thread) ----
  {
    const int oy = tid >> 3, ox = (tid & 7) * 4;
    const int gy = by + oy, gx = bx + ox;

    float4 gx4 = *reinterpret_cast<const float4*>(&sgx[oy * 32 + ox]);
    float4 gy4 = *reinterpret_cast<const float4*>(&sgy[oy * 32 + ox]);
    float gxa[4] = {gx4.x, gx4.y, gx4.z, gx4.w};
    float gya[4] = {gy4.x, gy4.y, gy4.z, gy4.w};

    float kap[4] = {0.f, 0.f, 0.f, 0.f};
    #pragma unroll
    for (int m5 = 0; m5 < 5; ++m5) {
      const float* row = &skp[(oy + m5) * 37 + ox];
      float r[8];
      #pragma unroll
      for (int t = 0; t < 8; ++t) r[t] = row[t];
      #pragma unroll
      for (int n = 0; n < 5; ++n) {
        float w = sm[m5 * 5 + n];
        #pragma unroll
        for (int t = 0; t < 4; ++t) kap[t] = fmaf(r[t + n], w, kap[t]);
      }
    }

    const float* ur = ub + (size_t)gy * WW + gx;
    float4 uc4 = *reinterpret_cast<const float4*>(ur);
    int jm = gx > 0 ? -1 : 0;
    float ul = ur[jm];
    ul = gx > 0 ? ul : 0.f;
    int ryd = gy < HH - 1 ? gy + 1 : HH - 1;
    float md = gy < HH - 1 ? 1.f : 0.f;
    float4 ud4 = *reinterpret_cast<const float4*>(ub + (size_t)ryd * WW + gx);

    float uc[4]  = {uc4.x, uc4.y, uc4.z, uc4.w};
    float ulx[4] = {ul, uc4.x, uc4.y, uc4.z};
    float udn[4] = {ud4.x * md, ud4.y * md, ud4.z * md, ud4.w * md};

    float res[4];
    #pragma unroll
    for (int t = 0; t < 4; ++t) {
      float xp = uc[t] - ulx[t];
      float yp = uc[t] - udn[t];
      float ec = bf2f(sebf[(oy + 1) * 36 + ox + 1 + t]);
      res[t] = uc[t] + gxa[t] * xp + gya[t] * yp + ec + kap[t];
    }
    *reinterpret_cast<float4*>(&out[((size_t)b * HH + gy) * WW + gx]) =
        make_float4(res[0], res[1], res[2], res[3]);
  }
}

// ---------------- Fallback: R3 monolith (used if ws too small) --------------
__global__ __launch_bounds__(256) void forcing_main(
    const float* __restrict__ u, const float* __restrict__ img,
    const float* __restrict__ kx, const float* __restrict__ ky,
    const float* __restrict__ sm, const float* __restrict__ kk,
    const float* __restrict__ ws, float* __restrict__ out) {
  __shared__ float su[46][48];
  __shared__ float si[36][37];
  __shared__ float se[34][35];
  __shared__ float sk[36][37];
  __shared__ float w_edge[72];
  __shared__ float w_kx[288];
  __shared__ float w_ky[288];
  __shared__ float w_k11[124];
  __shared__ float w_sm[28];

  const int bx = blockIdx.x * T;
  const int by = blockIdx.y * T;
  const int b  = blockIdx.z;
  const int tid = threadIdx.x;
  const float* ub = u   + (size_t)b * HH * WW;
  const float* ib = img + (size_t)b * HH * WW;

  for (int i = tid; i < 72; i += 256)  w_edge[i] = ws[i];
  for (int i = tid; i < 121; i += 256) w_k11[i]  = ws[72 + i];
  for (int i = tid; i < 288; i += 256) { w_kx[i] = kx[i]; w_ky[i] = ky[i]; }
  if (tid < 25) w_sm[tid] = sm[tid];

  for (int idx = tid; idx < 46 * 46; idx += 256) {
    int i = idx / 46, j = idx % 46;
    int gy = by - 7 + i, gx = bx - 7 + j;
    float v = 0.f;
    if ((unsigned)gy < HH && (unsigned)gx < WW) v = ub[gy * WW + gx];
    su[i][j] = v;
  }
  for (int idx = tid; idx < 36 * 36; idx += 256) {
    int i = idx / 36, j = idx % 36;
    int gy = by - 2 + i, gx = bx - 2 + j;
    float v = 0.f;
    if ((unsigned)gy < HH && (unsigned)gx < WW) v = ib[gy * WW + gx];
    si[i][j] = v;
  }
  __syncthreads();

  for (int idx = tid; idx < 34 * 9; idx += 256) {
    int i = idx / 9, j0 = (idx % 9) * 4;
    float acc[8][4];
    #pragma unroll
    for (int c = 0; c < 8; ++c)
      #pragma unroll
      for (int t = 0; t < 4; ++t) acc[c][t] = 0.f;
    #pragma unroll
    for (int p = 0; p < 3; ++p) {
      float r[6];
      #pragma unroll
      for (int t = 0; t < 6; ++t) r[t] = si[i + p][j0 + t];
      #pragma unroll
      for (int q = 0; q < 3; ++q) {
        const float4 w0 = *reinterpret_cast<const float4*>(&w_edge[(p * 3 + q) * 8]);
        const float4 w1 = *reinterpret_cast<const float4*>(&w_edge[(p * 3 + q) * 8 + 4]);
        #pragma unroll
        for (int t = 0; t < 4; ++t) {
          float v = r[q + t];
          acc[0][t] = fmaf(v, w0.x, acc[0][t]);
          acc[1][t] = fmaf(v, w0.y, acc[1][t]);
          acc[2][t] = fmaf(v, w0.z, acc[2][t]);
          acc[3][t] = fmaf(v, w0.w, acc[3][t]);
          acc[4][t] = fmaf(v, w1.x, acc[4][t]);
          acc[5][t] = fmaf(v, w1.y, acc[5][t]);
          acc[6][t] = fmaf(v, w1.z, acc[6][t]);
          acc[7][t] = fmaf(v, w1.w, acc[7][t]);
        }
      }
    }
    int gy = by - 1 + i;
    #pragma unroll
    for (int t = 0; t < 4; ++t) {
      int j = j0 + t;
      if (j < 34) {
        int gx = bx - 1 + j;
        float val = 0.f;
        if ((unsigned)gy < HH && (unsigned)gx < WW) {
          float e = 0.f;
          #pragma unroll
          for (int c = 0; c < 8; ++c) e += fmaxf(acc[c][t], 0.f);
          val = e / (1.f + e);
        }
        se[i][j] = val;
      }
    }
  }

  for (int idx = tid; idx < 36 * 9; idx += 256) {
    int i = idx / 9, js = (idx % 9) * 4;
    float o0 = 0.f, o1 = 0.f, o2 = 0.f, o3 = 0.f;
    #pragma unroll
    for (int A = 0; A < 11; ++A) {
      const float* row = &su[i + A][js];
      float4 v0 = *reinterpret_cast<const float4*>(row);
      float4 v1 = *reinterpret_cast<const float4*>(row + 4);
      float4 v2 = *reinterpret_cast<const float4*>(row + 8);
      float r[14] = {v0.x, v0.y, v0.z, v0.w, v1.x, v1.y, v1.z, v1.w,
                     v2.x, v2.y, v2.z, v2.w, row[12], row[13]};
      #pragma unroll
      for (int B2 = 0; B2 < 11; ++B2) {
        float w = w_k11[A * 11 + B2];
        o0 = fmaf(r[B2],     w, o0);
        o1 = fmaf(r[B2 + 1], w, o1);
        o2 = fmaf(r[B2 + 2], w, o2);
        o3 = fmaf(r[B2 + 3], w, o3);
      }
    }
    int gy = by - 2 + i;
    float o[4] = {o0, o1, o2, o3};
    #pragma unroll
    for (int t = 0; t < 4; ++t) {
      int gx = bx - 2 + js + t;
      float val = 0.f;
      if ((unsigned)gy < HH && (unsigned)gx < WW) val = o[t] * kk[gy * WW + gx];
      sk[i][js + t] = val;
    }
  }
  __syncthreads();

  {
    const int oy = tid >> 3;
    const int ox = (tid & 7) * 4;
    const int gy = by + oy;
    const int gx = bx + ox;

    float e[3][6];
    #pragma unroll
    for (int p = 0; p < 3; ++p)
      #pragma unroll
      for (int t = 0; t < 6; ++t) e[p][t] = se[oy + p][ox + t];

    const float4* wx4 = reinterpret_cast<const float4*>(w_kx);
    const float4* wy4 = reinterpret_cast<const float4*>(w_ky);

    float gxa[4] = {0.f, 0.f, 0.f, 0.f};
    float gya[4] = {0.f, 0.f, 0.f, 0.f};
    #pragma unroll
    for (int cq = 0; cq < 8; ++cq) {
      float sx[4][4], sy[4][4];
      #pragma unroll
      for (int cc = 0; cc < 4; ++cc)
        #pragma unroll
        for (int t = 0; t < 4; ++t) { sx[cc][t] = 0.f; sy[cc][t] = 0.f; }
      #pragma unroll
      for (int p = 0; p < 3; ++p)
        #pragma unroll
        for (int q = 0; q < 3; ++q) {
          float4 wx = wx4[(p * 3 + q) * 8 + cq];
          float4 wy = wy4[(p * 3 + q) * 8 + cq];
          #pragma unroll
          for (int t = 0; t < 4; ++t) {
            float evv = e[p][q + t];
            sx[0][t] = fmaf(evv, wx.x, sx[0][t]);
            sx[1][t] = fmaf(evv, wx.y, sx[1][t]);
            sx[2][t] = fmaf(evv, wx.z, sx[2][t]);
            sx[3][t] = fmaf(evv, wx.w, sx[3][t]);
            sy[0][t] = fmaf(evv, wy.x, sy[0][t]);
            sy[1][t] = fmaf(evv, wy.y, sy[1][t]);
            sy[2][t] = fmaf(evv, wy.z, sy[2][t]);
            sy[3][t] = fmaf(evv, wy.w, sy[3][t]);
          }
        }
      #pragma unroll
      for (int cc = 0; cc < 4; ++cc)
        #pragma unroll
        for (int t = 0; t < 4; ++t) {
          gxa[t] += fmaxf(sx[cc][t], 0.f);
          gya[t] += fmaxf(sy[cc][t], 0.f);
        }
    }

    float res[4];
    #pragma unroll
    for (int t = 0; t < 4; ++t) {
      float kap = 0.f;
      #pragma unroll
      for (int m = 0; m < 5; ++m)
        #pragma unroll
        for (int n = 0; n < 5; ++n)
          kap = fmaf(sk[oy + m][ox + t + n], w_sm[m * 5 + n], kap);

      float uc = su[oy + 7][ox + 7 + t];
      float xp = uc - su[oy + 7][ox + 6 + t];
      float yp = uc - su[oy + 8][ox + 7 + t];
      float ec = se[oy + 1][ox + 1 + t];
      res[t] = uc + gxa[t] * xp + gya[t] * yp + ec + kap;
    }

    float4 r4 = make_float4(res[0], res[1], res[2], res[3]);
    *reinterpret_cast<float4*>(&out[((size_t)b * HH + gy) * WW + gx]) = r4;
  }
}

extern "C" void kernel_launch(void* const* d_in, const int* in_sizes, int n_in,
                              void* d_out, int out_size, void* d_ws, size_t ws_size,
                              hipStream_t stream) {
  const float* u   = (const float*)d_in[0];
  const float* img = (const float*)d_in[1];
  const float* kx  = (const float*)d_in[2];
  const float* ky  = (const float*)d_in[3];
  const float* kd  = (const float*)d_in[4];
  const float* kp  = (const float*)d_in[5];
  const float* k0  = (const float*)d_in[6];
  const float* k1  = (const float*)d_in[7];
  const float* k2  = (const float*)d_in[8];
  const float* sm  = (const float*)d_in[9];
  const float* kk  = (const float*)d_in[10];
  float* out = (float*)d_out;
  float* ws  = (float*)d_ws;

  precompute_kernels<<<1, 256, 0, stream>>>(kd, kp, k0, k1, k2, kx, ky, ws);
  dim3 grid(WW / T, HH / T, BB);
  if (ws != nullptr && ws_size >= WS_NEEDED_BYTES) {
    fused<<<grid, 256, 0, stream>>>(u, img, kk, sm, ws, out);
  } else {
    forcing_main<<<grid, 256, 0, stream>>>(u, img, kx, ky, sm, kk, ws, out);
  }
}

// Round 15
// 148.209 us; speedup vs baseline: 1.0292x; 1.0292x over previous
//
#include <hip/hip_runtime.h>
#include <cstddef>

#define HH 512
#define WW 512
#define BB 8
#define T  32

// ws layout (floats):
//   [0..72)      keff_edge  (3*3)*8ch
//   [72..193)    Keff11     11*11
//   [256..1280)  F-bank (grad filters): 4 tiles x 64 lanes x 8 bf16
//   [1280..4096) KT-bank (kappa Toeplitz): 11 b x 64 lanes x 8 bf16
//                KT_b[m=lane&15][k=(lane>>4)*8+j] = Keff11[k-m-3][b] if 0<=k-m-3<11
#define F0    256
#define KT0   1280
#define WS_NEEDED_BYTES ((size_t)4096 * 4)

typedef __attribute__((ext_vector_type(8))) short short8;
typedef __attribute__((ext_vector_type(4))) float float4v;

__device__ inline unsigned short f2bf(float f) {   // fp32 -> bf16 RNE
  unsigned u = __builtin_bit_cast(unsigned, f);
  unsigned r = (u + 0x7FFFu + ((u >> 16) & 1u)) >> 16;
  return (unsigned short)r;
}
__device__ inline float bf2f(unsigned short h) {
  unsigned u = ((unsigned)h) << 16;
  return __builtin_bit_cast(float, u);
}

__global__ __launch_bounds__(256) void precompute_kernels(
    const float* __restrict__ kd,   // (3,3,1,8)
    const float* __restrict__ kp,   // (1,1,8,8)
    const float* __restrict__ k0,   // (5,5,1,8)
    const float* __restrict__ k1,   // (5,5,8,8)
    const float* __restrict__ k2,   // (3,3,8,16)
    const float* __restrict__ kx,   // (3,3,1,32)
    const float* __restrict__ ky,   // (3,3,1,32)
    float* __restrict__ ws) {
  __shared__ float k9[648];
  __shared__ float k2s[72];
  __shared__ float kef[121];
  const int tid = threadIdx.x;

  for (int idx = tid; idx < 72; idx += 256) {
    int c = idx & 7, pq = idx >> 3;
    float s = 0.f;
    for (int c0 = 0; c0 < 8; ++c0) s = fmaf(kd[pq * 8 + c0], kp[c0 * 8 + c], s);
    ws[idx] = s;
  }
  for (int idx = tid; idx < 72; idx += 256) {
    int c1 = idx & 7, tv = idx >> 3;
    float s = 0.f;
    for (int c2 = 0; c2 < 16; ++c2) s += k2[(tv * 8 + c1) * 16 + c2];
    k2s[idx] = s;
  }
  for (int idx = tid; idx < 648; idx += 256) {
    int c1 = idx & 7;
    int ab = idx >> 3;
    int a = ab / 9, b = ab % 9;
    float s = 0.f;
    int plo = a > 4 ? a - 4 : 0, phi = a < 4 ? a : 4;
    int qlo = b > 4 ? b - 4 : 0, qhi = b < 4 ? b : 4;
    for (int p = plo; p <= phi; ++p)
      for (int q = qlo; q <= qhi; ++q) {
        int r = a - p, sx = b - q;
        const float* k0p = &k0[(p * 5 + q) * 8];
        const float* k1p = &k1[((r * 5 + sx) * 8) * 8 + c1];
        for (int c0 = 0; c0 < 8; ++c0) s = fmaf(k0p[c0], k1p[c0 * 8], s);
      }
    k9[idx] = s;
  }
  // F-bank (grad filters)
  for (int idx = tid; idx < 2048; idx += 256) {
    int nt = idx >> 9, ln = (idx >> 3) & 63, j = idx & 7;
    int k = (ln >> 4) * 8 + j;
    int n = nt * 16 + (ln & 15);
    float v = 0.f;
    if (k < 9) v = (n < 32) ? kx[k * 32 + n] : ky[k * 32 + (n - 32)];
    ((unsigned short*)ws)[F0 * 2 + idx] = f2bf(v);
  }
  __syncthreads();
  for (int idx = tid; idx < 121; idx += 256) {
    int A = idx / 11, B = idx % 11;
    float s = 0.f;
    int tlo = A > 8 ? A - 8 : 0, thi = A < 2 ? A : 2;
    int vlo = B > 8 ? B - 8 : 0, vhi = B < 2 ? B : 2;
    for (int t = tlo; t <= thi; ++t)
      for (int v = vlo; v <= vhi; ++v) {
        int a = A - t, b = B - v;
        for (int c1 = 0; c1 < 8; ++c1)
          s = fmaf(k9[(a * 9 + b) * 8 + c1], k2s[(t * 3 + v) * 8 + c1], s);
      }
    ws[72 + idx] = s;
    kef[idx] = s;
  }
  __syncthreads();
  // KT-bank: kappa Toeplitz A-frags (bf16)
  for (int idx = tid; idx < 5632; idx += 256) {
    int b = idx >> 9, ln = (idx >> 3) & 63, j = idx & 7;
    int m = ln & 15;
    int k = (ln >> 4) * 8 + j;
    int a = k - m - 3;
    float v = ((unsigned)a < 11u) ? kef[a * 11 + b] : 0.f;
    ((unsigned short*)ws)[KT0 * 2 + idx] = f2bf(v);
  }
}

// ---------------- fused kernel v3: 2 barriers, no sgx/sgy -------------------
// R15: (a) staging back to row-major (coalesced global; R14's column staging
// un-coalesced global reads, FETCH +10%); (b) combine merged into phase 2 —
// after the 2-shuffle reduction every lane holds the grad sums, so lane (q,m)
// keeps rxv/ryv[8] in registers and finalizes pixels (wv*8+2q+s, h+m)
// directly. Deletes sgx/sgy (8 KB) and the third barrier. LDS 21312 B.
__global__ __launch_bounds__(256) void fused(
    const float* __restrict__ u, const float* __restrict__ img,
    const float* __restrict__ kk, const float* __restrict__ sm,
    const float* __restrict__ ws, float* __restrict__ out) {
  __shared__ unsigned short suT[58 * 72]; // u transposed bf16 [col][row], stride 72
                                          // cols bx-7..bx+50, rows by-10..by+53
  __shared__ float si[36 * 36];           // image tile, r=2 halo, origin (by-2,bx-2)
  __shared__ unsigned short sebf[34 * 36];// edges bf16 (grad MFMA + combine center)
  __shared__ float skp[36 * 37];          // kappa*kk, r=2 halo (smoother input)

  const int bx = blockIdx.x * T, by = blockIdx.y * T, b = blockIdx.z;
  const int tid = threadIdx.x;
  const float* ub = u + (size_t)b * HH * WW;
  const float* ib = img + (size_t)b * HH * WW;

  const int lane = tid & 63;
  const int wv   = tid >> 6;
  const int q    = lane >> 4;
  const int m    = lane & 15;

  // ---- phase 0: stage (row-major: coalesced global reads) ----
  for (int idx = tid; idx < 64 * 58; idx += 256) {
    int r = idx / 58, c = idx % 58;
    int gy = by - 10 + r, gx = bx - 7 + c;
    float v = 0.f;
    if ((unsigned)gy < HH && (unsigned)gx < WW) v = ub[gy * WW + gx];
    suT[c * 72 + r] = f2bf(v);
  }
  for (int idx = tid; idx < 36 * 36; idx += 256) {
    int i = idx / 36, j = idx % 36;
    int gy = by - 2 + i, gx = bx - 2 + j;
    float v = 0.f;
    if ((unsigned)gy < HH && (unsigned)gx < WW) v = ib[gy * WW + gx];
    si[i * 36 + j] = v;
  }
  __syncthreads();

  // ---- phase 1a: edges on 34x34 (strips of 4) ----
  for (int idx = tid; idx < 34 * 9; idx += 256) {
    int i = idx / 9, j0 = (idx % 9) * 4;
    float acc[8][4];
    #pragma unroll
    for (int c = 0; c < 8; ++c)
      #pragma unroll
      for (int t = 0; t < 4; ++t) acc[c][t] = 0.f;
    #pragma unroll
    for (int p = 0; p < 3; ++p) {
      float r[6];
      #pragma unroll
      for (int t = 0; t < 6; ++t) r[t] = si[(i + p) * 36 + j0 + t];
      #pragma unroll
      for (int qq = 0; qq < 3; ++qq) {
        float4 w0 = *reinterpret_cast<const float4*>(&ws[(p * 3 + qq) * 8]);
        float4 w1 = *reinterpret_cast<const float4*>(&ws[(p * 3 + qq) * 8 + 4]);
        #pragma unroll
        for (int t = 0; t < 4; ++t) {
          float v = r[qq + t];
          acc[0][t] = fmaf(v, w0.x, acc[0][t]);
          acc[1][t] = fmaf(v, w0.y, acc[1][t]);
          acc[2][t] = fmaf(v, w0.z, acc[2][t]);
          acc[3][t] = fmaf(v, w0.w, acc[3][t]);
          acc[4][t] = fmaf(v, w1.x, acc[4][t]);
          acc[5][t] = fmaf(v, w1.y, acc[5][t]);
          acc[6][t] = fmaf(v, w1.z, acc[6][t]);
          acc[7][t] = fmaf(v, w1.w, acc[7][t]);
        }
      }
    }
    int gy = by - 1 + i;
    #pragma unroll
    for (int t = 0; t < 4; ++t) {
      int j = j0 + t;
      if (j < 34) {
        int gx = bx - 1 + j;
        float val = 0.f;
        if ((unsigned)gy < HH && (unsigned)gx < WW) {
          float e = 0.f;
          #pragma unroll
          for (int c = 0; c < 8; ++c) e += fmaxf(acc[c][t], 0.f);
          val = e / (1.f + e);
        }
        sebf[i * 36 + j] = f2bf(val);
      }
    }
  }

  // ---- phase 1b: kappa via Toeplitz MFMA, 9 subtiles -> skp 36x36 ----
  {
    const unsigned short* KT = ((const unsigned short*)ws) + KT0 * 2;
    for (int s = wv; s < 9; s += 4) {
      int sty = s / 3, stx = s % 3;
      float4v acc = {0.f, 0.f, 0.f, 0.f};
      #pragma unroll
      for (int bb = 0; bb < 11; ++bb) {
        short8 af = *reinterpret_cast<const short8*>(KT + (bb * 64 + lane) * 8);
        short8 bf = *reinterpret_cast<const short8*>(
            &suT[(stx * 16 + m + bb) * 72 + sty * 16 + q * 8]);
        acc = __builtin_amdgcn_mfma_f32_16x16x32_bf16(af, bf, acc, 0, 0, 0);
      }
      #pragma unroll
      for (int i = 0; i < 4; ++i) {
        int rl = sty * 16 + q * 4 + i, cl = stx * 16 + m;
        if (rl < 36 && cl < 36) {
          int yy = by - 2 + rl, xx = bx - 2 + cl;
          float v = 0.f;
          if ((unsigned)yy < HH && (unsigned)xx < WW)
            v = acc[i] * kk[(size_t)yy * WW + xx];
          skp[rl * 37 + cl] = v;
        }
      }
    }
  }
  __syncthreads();

  // ---- phase 2: grads via transposed MFMA + inline combine ----
  {
    short8 afr[4];
    const unsigned short* F = ((const unsigned short*)ws) + F0 * 2;
    #pragma unroll
    for (int t = 0; t < 4; ++t)
      afr[t] = *reinterpret_cast<const short8*>(F + (t * 64 + lane) * 8);

    #pragma unroll
    for (int h = 0; h < 32; h += 16) {
      const int cl = h + m;                 // pixel col (tile-local)
      unsigned short W[9];
      #pragma unroll
      for (int d = 0; d < 3; ++d) {
        const unsigned short* rp = &sebf[(wv * 8 + d) * 36 + cl];
        W[3 * d + 0] = rp[0]; W[3 * d + 1] = rp[1]; W[3 * d + 2] = rp[2];
      }

      float rxv[8], ryv[8];
      #pragma unroll
      for (int r = 0; r < 8; ++r) {
        short8 bv = (short8)0;
        if (q == 0) {
          #pragma unroll
          for (int j = 0; j < 8; ++j) bv[j] = (short)W[j];
        } else if (q == 1) {
          bv[0] = (short)W[8];
        }

        float4v c0 = {0.f, 0.f, 0.f, 0.f}, c1 = c0, c2 = c0, c3 = c0;
        c0 = __builtin_amdgcn_mfma_f32_16x16x32_bf16(afr[0], bv, c0, 0, 0, 0);
        c1 = __builtin_amdgcn_mfma_f32_16x16x32_bf16(afr[1], bv, c1, 0, 0, 0);
        c2 = __builtin_amdgcn_mfma_f32_16x16x32_bf16(afr[2], bv, c2, 0, 0, 0);
        c3 = __builtin_amdgcn_mfma_f32_16x16x32_bf16(afr[3], bv, c3, 0, 0, 0);

        float rx = 0.f, ry = 0.f;
        #pragma unroll
        for (int i = 0; i < 4; ++i) {
          rx += fmaxf(c0[i], 0.f) + fmaxf(c1[i], 0.f);
          ry += fmaxf(c2[i], 0.f) + fmaxf(c3[i], 0.f);
        }
        rx += __shfl_xor(rx, 16); rx += __shfl_xor(rx, 32);
        ry += __shfl_xor(ry, 16); ry += __shfl_xor(ry, 32);
        rxv[r] = rx; ryv[r] = ry;

        if (r < 7) {
          #pragma unroll
          for (int t = 0; t < 6; ++t) W[t] = W[t + 3];
          const unsigned short* rp = &sebf[(wv * 8 + r + 3) * 36 + cl];
          W[6] = rp[0]; W[7] = rp[1]; W[8] = rp[2];
        }
      }

      // inline combine: lane (q,m) -> pixels (wv*8 + 2q + s, h + m), s=0,1
      {
        const int row0 = wv * 8 + 2 * q;       // tile-local pixel row base
        const int gx = bx + cl;
        float sk6[6][5];                        // 6 rows x 5 cols smoother window
        #pragma unroll
        for (int rr = 0; rr < 6; ++rr)
          #pragma unroll
          for (int n = 0; n < 5; ++n)
            sk6[rr][n] = skp[(row0 + rr) * 37 + cl + n];

        #pragma unroll
        for (int s = 0; s < 2; ++s) {
          int oy = row0 + s;
          int gy = by + oy;
          float kap = 0.f;
          #pragma unroll
          for (int m5 = 0; m5 < 5; ++m5)
            #pragma unroll
            for (int n = 0; n < 5; ++n)
              kap = fmaf(sk6[s + m5][n], sm[m5 * 5 + n], kap);

          float ec = bf2f(sebf[(oy + 1) * 36 + cl + 1]);
          const float* ur = ub + (size_t)gy * WW + gx;
          float uc = ur[0];
          float ul = gx > 0 ? ur[-1] : 0.f;
          float ud = gy < HH - 1 ? ur[WW] : 0.f;
          float xp = uc - ul;
          float yp = uc - ud;
          out[((size_t)b * HH + gy) * WW + gx] =
              uc + rxv[2 * q + s] * xp + ryv[2 * q + s] * yp + ec + kap;
        }
      }
    }
  }
}

// ---------------- Fallback: R3 monolith (used if ws too small) --------------
__global__ __launch_bounds__(256) void forcing_main(
    const float* __restrict__ u, const float* __restrict__ img,
    const float* __restrict__ kx, const float* __restrict__ ky,
    const float* __restrict__ sm, const float* __restrict__ kk,
    const float* __restrict__ ws, float* __restrict__ out) {
  __shared__ float su[46][48];
  __shared__ float si[36][37];
  __shared__ float se[34][35];
  __shared__ float sk[36][37];
  __shared__ float w_edge[72];
  __shared__ float w_kx[288];
  __shared__ float w_ky[288];
  __shared__ float w_k11[124];
  __shared__ float w_sm[28];

  const int bx = blockIdx.x * T;
  const int by = blockIdx.y * T;
  const int b  = blockIdx.z;
  const int tid = threadIdx.x;
  const float* ub = u   + (size_t)b * HH * WW;
  const float* ib = img + (size_t)b * HH * WW;

  for (int i = tid; i < 72; i += 256)  w_edge[i] = ws[i];
  for (int i = tid; i < 121; i += 256) w_k11[i]  = ws[72 + i];
  for (int i = tid; i < 288; i += 256) { w_kx[i] = kx[i]; w_ky[i] = ky[i]; }
  if (tid < 25) w_sm[tid] = sm[tid];

  for (int idx = tid; idx < 46 * 46; idx += 256) {
    int i = idx / 46, j = idx % 46;
    int gy = by - 7 + i, gx = bx - 7 + j;
    float v = 0.f;
    if ((unsigned)gy < HH && (unsigned)gx < WW) v = ub[gy * WW + gx];
    su[i][j] = v;
  }
  for (int idx = tid; idx < 36 * 36; idx += 256) {
    int i = idx / 36, j = idx % 36;
    int gy = by - 2 + i, gx = bx - 2 + j;
    float v = 0.f;
    if ((unsigned)gy < HH && (unsigned)gx < WW) v = ib[gy * WW + gx];
    si[i][j] = v;
  }
  __syncthreads();

  for (int idx = tid; idx < 34 * 9; idx += 256) {
    int i = idx / 9, j0 = (idx % 9) * 4;
    float acc[8][4];
    #pragma unroll
    for (int c = 0; c < 8; ++c)
      #pragma unroll
      for (int t = 0; t < 4; ++t) acc[c][t] = 0.f;
    #pragma unroll
    for (int p = 0; p < 3; ++p) {
      float r[6];
      #pragma unroll
      for (int t = 0; t < 6; ++t) r[t] = si[i + p][j0 + t];
      #pragma unroll
      for (int q = 0; q < 3; ++q) {
        const float4 w0 = *reinterpret_cast<const float4*>(&w_edge[(p * 3 + q) * 8]);
        const float4 w1 = *reinterpret_cast<const float4*>(&w_edge[(p * 3 + q) * 8 + 4]);
        #pragma unroll
        for (int t = 0; t < 4; ++t) {
          float v = r[q + t];
          acc[0][t] = fmaf(v, w0.x, acc[0][t]);
          acc[1][t] = fmaf(v, w0.y, acc[1][t]);
          acc[2][t] = fmaf(v, w0.z, acc[2][t]);
          acc[3][t] = fmaf(v, w0.w, acc[3][t]);
          acc[4][t] = fmaf(v, w1.x, acc[4][t]);
          acc[5][t] = fmaf(v, w1.y, acc[5][t]);
          acc[6][t] = fmaf(v, w1.z, acc[6][t]);
          acc[7][t] = fmaf(v, w1.w, acc[7][t]);
        }
      }
    }
    int gy = by - 1 + i;
    #pragma unroll
    for (int t = 0; t < 4; ++t) {
      int j = j0 + t;
      if (j < 34) {
        int gx = bx - 1 + j;
        float val = 0.f;
        if ((unsigned)gy < HH && (unsigned)gx < WW) {
          float e = 0.f;
          #pragma unroll
          for (int c = 0; c < 8; ++c) e += fmaxf(acc[c][t], 0.f);
          val = e / (1.f + e);
        }
        se[i][j] = val;
      }
    }
  }

  for (int idx = tid; idx < 36 * 9; idx += 256) {
    int i = idx / 9, js = (idx % 9) * 4;
    float o0 = 0.f, o1 = 0.f, o2 = 0.f, o3 = 0.f;
    #pragma unroll
    for (int A = 0; A < 11; ++A) {
      const float* row = &su[i + A][js];
      float4 v0 = *reinterpret_cast<const float4*>(row);
      float4 v1 = *reinterpret_cast<const float4*>(row + 4);
      float4 v2 = *reinterpret_cast<const float4*>(row + 8);
      float r[14] = {v0.x, v0.y, v0.z, v0.w, v1.x, v1.y, v1.z, v1.w,
                     v2.x, v2.y, v2.z, v2.w, row[12], row[13]};
      #pragma unroll
      for (int B2 = 0; B2 < 11; ++B2) {
        float w = w_k11[A * 11 + B2];
        o0 = fmaf(r[B2],     w, o0);
        o1 = fmaf(r[B2 + 1], w, o1);
        o2 = fmaf(r[B2 + 2], w, o2);
        o3 = fmaf(r[B2 + 3], w, o3);
      }
    }
    int gy = by - 2 + i;
    float o[4] = {o0, o1, o2, o3};
    #pragma unroll
    for (int t = 0; t < 4; ++t) {
      int gx = bx - 2 + js + t;
      float val = 0.f;
      if ((unsigned)gy < HH && (unsigned)gx < WW) val = o[t] * kk[gy * WW + gx];
      sk[i][js + t] = val;
    }
  }
  __syncthreads();

  {
    const int oy = tid >> 3;
    const int ox = (tid & 7) * 4;
    const int gy = by + oy;
    const int gx = bx + ox;

    float e[3][6];
    #pragma unroll
    for (int p = 0; p < 3; ++p)
      #pragma unroll
      for (int t = 0; t < 6; ++t) e[p][t] = se[oy + p][ox + t];

    const float4* wx4 = reinterpret_cast<const float4*>(w_kx);
    const float4* wy4 = reinterpret_cast<const float4*>(w_ky);

    float gxa[4] = {0.f, 0.f, 0.f, 0.f};
    float gya[4] = {0.f, 0.f, 0.f, 0.f};
    #pragma unroll
    for (int cq = 0; cq < 8; ++cq) {
      float sx[4][4], sy[4][4];
      #pragma unroll
      for (int cc = 0; cc < 4; ++cc)
        #pragma unroll
        for (int t = 0; t < 4; ++t) { sx[cc][t] = 0.f; sy[cc][t] = 0.f; }
      #pragma unroll
      for (int p = 0; p < 3; ++p)
        #pragma unroll
        for (int q = 0; q < 3; ++q) {
          float4 wx = wx4[(p * 3 + q) * 8 + cq];
          float4 wy = wy4[(p * 3 + q) * 8 + cq];
          #pragma unroll
          for (int t = 0; t < 4; ++t) {
            float evv = e[p][q + t];
            sx[0][t] = fmaf(evv, wx.x, sx[0][t]);
            sx[1][t] = fmaf(evv, wx.y, sx[1][t]);
            sx[2][t] = fmaf(evv, wx.z, sx[2][t]);
            sx[3][t] = fmaf(evv, wx.w, sx[3][t]);
            sy[0][t] = fmaf(evv, wy.x, sy[0][t]);
            sy[1][t] = fmaf(evv, wy.y, sy[1][t]);
            sy[2][t] = fmaf(evv, wy.z, sy[2][t]);
            sy[3][t] = fmaf(evv, wy.w, sy[3][t]);
          }
        }
      #pragma unroll
      for (int cc = 0; cc < 4; ++cc)
        #pragma unroll
        for (int t = 0; t < 4; ++t) {
          gxa[t] += fmaxf(sx[cc][t], 0.f);
          gya[t] += fmaxf(sy[cc][t], 0.f);
        }
    }

    float res[4];
    #pragma unroll
    for (int t = 0; t < 4; ++t) {
      float kap = 0.f;
      #pragma unroll
      for (int m = 0; m < 5; ++m)
        #pragma unroll
        for (int n = 0; n < 5; ++n)
          kap = fmaf(sk[oy + m][ox + t + n], w_sm[m * 5 + n], kap);

      float uc = su[oy + 7][ox + 7 + t];
      float xp = uc - su[oy + 7][ox + 6 + t];
      float yp = uc - su[oy + 8][ox + 7 + t];
      float ec = se[oy + 1][ox + 1 + t];
      res[t] = uc + gxa[t] * xp + gya[t] * yp + ec + kap;
    }

    float4 r4 = make_float4(res[0], res[1], res[2], res[3]);
    *reinterpret_cast<float4*>(&out[((size_t)b * HH + gy) * WW + gx]) = r4;
  }
}

extern "C" void kernel_launch(void* const* d_in, const int* in_sizes, int n_in,
                              void* d_out, int out_size, void* d_ws, size_t ws_size,
                              hipStream_t stream) {
  const float* u   = (const float*)d_in[0];
  const float* img = (const float*)d_in[1];
  const float* kx  = (const float*)d_in[2];
  const float* ky  = (const float*)d_in[3];
  const float* kd  = (const float*)d_in[4];
  const float* kp  = (const float*)d_in[5];
  const float* k0  = (const float*)d_in[6];
  const float* k1  = (const float*)d_in[7];
  const float* k2  = (const float*)d_in[8];
  const float* sm  = (const float*)d_in[9];
  const float* kk  = (const float*)d_in[10];
  float* out = (float*)d_out;
  float* ws  = (float*)d_ws;

  precompute_kernels<<<1, 256, 0, stream>>>(kd, kp, k0, k1, k2, kx, ky, ws);
  dim3 grid(WW / T, HH / T, BB);
  if (ws != nullptr && ws_size >= WS_NEEDED_BYTES) {
    fused<<<grid, 256, 0, stream>>>(u, img, kk, sm, ws, out);
  } else {
    forcing_main<<<grid, 256, 0, stream>>>(u, img, kx, ky, sm, kk, ws, out);
  }
}

// Round 16
// 143.638 us; speedup vs baseline: 1.0620x; 1.0318x over previous
//
#include <hip/hip_runtime.h>
#include <cstddef>

#define HH 512
#define WW 512
#define BB 8
#define TX 64
#define TY 32

// ws layout (floats):
//   [0..72)      keff_edge  (3*3)*8ch
//   [72..193)    Keff11     11*11
//   [256..1280)  F-bank (grad filters): 4 tiles x 64 lanes x 8 bf16
//   [1280..4096) KT-bank (kappa Toeplitz): 11 b x 64 lanes x 8 bf16
//                KT_b[m=lane&15][k=(lane>>4)*8+j] = Keff11[k-m-3][b] if 0<=k-m-3<11
#define F0    256
#define KT0   1280
#define WS_NEEDED_BYTES ((size_t)4096 * 4)

typedef __attribute__((ext_vector_type(8))) short short8;
typedef __attribute__((ext_vector_type(4))) float float4v;

__device__ inline unsigned short f2bf(float f) {   // fp32 -> bf16 RNE
  unsigned u = __builtin_bit_cast(unsigned, f);
  unsigned r = (u + 0x7FFFu + ((u >> 16) & 1u)) >> 16;
  return (unsigned short)r;
}
__device__ inline float bf2f(unsigned short h) {
  unsigned u = ((unsigned)h) << 16;
  return __builtin_bit_cast(float, u);
}

__global__ __launch_bounds__(256) void precompute_kernels(
    const float* __restrict__ kd,   // (3,3,1,8)
    const float* __restrict__ kp,   // (1,1,8,8)
    const float* __restrict__ k0,   // (5,5,1,8)
    const float* __restrict__ k1,   // (5,5,8,8)
    const float* __restrict__ k2,   // (3,3,8,16)
    const float* __restrict__ kx,   // (3,3,1,32)
    const float* __restrict__ ky,   // (3,3,1,32)
    float* __restrict__ ws) {
  __shared__ float k9[648];
  __shared__ float k2s[72];
  __shared__ float kef[121];
  const int tid = threadIdx.x;

  for (int idx = tid; idx < 72; idx += 256) {
    int c = idx & 7, pq = idx >> 3;
    float s = 0.f;
    for (int c0 = 0; c0 < 8; ++c0) s = fmaf(kd[pq * 8 + c0], kp[c0 * 8 + c], s);
    ws[idx] = s;
  }
  for (int idx = tid; idx < 72; idx += 256) {
    int c1 = idx & 7, tv = idx >> 3;
    float s = 0.f;
    for (int c2 = 0; c2 < 16; ++c2) s += k2[(tv * 8 + c1) * 16 + c2];
    k2s[idx] = s;
  }
  for (int idx = tid; idx < 648; idx += 256) {
    int c1 = idx & 7;
    int ab = idx >> 3;
    int a = ab / 9, b = ab % 9;
    float s = 0.f;
    int plo = a > 4 ? a - 4 : 0, phi = a < 4 ? a : 4;
    int qlo = b > 4 ? b - 4 : 0, qhi = b < 4 ? b : 4;
    for (int p = plo; p <= phi; ++p)
      for (int q = qlo; q <= qhi; ++q) {
        int r = a - p, sx = b - q;
        const float* k0p = &k0[(p * 5 + q) * 8];
        const float* k1p = &k1[((r * 5 + sx) * 8) * 8 + c1];
        for (int c0 = 0; c0 < 8; ++c0) s = fmaf(k0p[c0], k1p[c0 * 8], s);
      }
    k9[idx] = s;
  }
  // F-bank (grad filters)
  for (int idx = tid; idx < 2048; idx += 256) {
    int nt = idx >> 9, ln = (idx >> 3) & 63, j = idx & 7;
    int k = (ln >> 4) * 8 + j;
    int n = nt * 16 + (ln & 15);
    float v = 0.f;
    if (k < 9) v = (n < 32) ? kx[k * 32 + n] : ky[k * 32 + (n - 32)];
    ((unsigned short*)ws)[F0 * 2 + idx] = f2bf(v);
  }
  __syncthreads();
  for (int idx = tid; idx < 121; idx += 256) {
    int A = idx / 11, B = idx % 11;
    float s = 0.f;
    int tlo = A > 8 ? A - 8 : 0, thi = A < 2 ? A : 2;
    int vlo = B > 8 ? B - 8 : 0, vhi = B < 2 ? B : 2;
    for (int t = tlo; t <= thi; ++t)
      for (int v = vlo; v <= vhi; ++v) {
        int a = A - t, b = B - v;
        for (int c1 = 0; c1 < 8; ++c1)
          s = fmaf(k9[(a * 9 + b) * 8 + c1], k2s[(t * 3 + v) * 8 + c1], s);
      }
    ws[72 + idx] = s;
    kef[idx] = s;
  }
  __syncthreads();
  // KT-bank: kappa Toeplitz A-frags (bf16)
  for (int idx = tid; idx < 5632; idx += 256) {
    int b = idx >> 9, ln = (idx >> 3) & 63, j = idx & 7;
    int m = ln & 15;
    int k = (ln >> 4) * 8 + j;
    int a = k - m - 3;
    float v = ((unsigned)a < 11u) ? kef[a * 11 + b] : 0.f;
    ((unsigned short*)ws)[KT0 * 2 + idx] = f2bf(v);
  }
}

// ---------------- fused kernel v4: 64x32 tiles ------------------------------
// R16: 2x-wide tiles (1024 blocks). Per-px halo work drops ~20%, each phase
// runs 2x iterations per latency-chain instance (amortization), half the
// barrier/launch instances. LDS ~37.6 KB -> 4 blocks/CU.
__global__ __launch_bounds__(256) void fused(
    const float* __restrict__ u, const float* __restrict__ img,
    const float* __restrict__ kk, const float* __restrict__ sm,
    const float* __restrict__ ws, float* __restrict__ out) {
  __shared__ unsigned short suT[90 * 72]; // u transposed bf16 [col][row], stride 72
                                          // staged cols bx-7..bx+70 (78), rows by-10..by+53 (64)
                                          // cols 78..89 unstaged (masked-lane reads only)
  __shared__ float si[36 * 70];           // image, rows by-2..by+33, cols bx-2..bx+67
  __shared__ unsigned short sebf[34 * 68];// edges bf16, rows by-1..by+32, cols bx-1..bx+64 (66 used)
  __shared__ float skp[36 * 69];          // kappa*kk, rows by-2..by+33, cols bx-2..bx+65 (68 used)

  const int bx = blockIdx.x * TX, by = blockIdx.y * TY, b = blockIdx.z;
  const int tid = threadIdx.x;
  const float* ub = u + (size_t)b * HH * WW;
  const float* ib = img + (size_t)b * HH * WW;

  const int lane = tid & 63;
  const int wv   = tid >> 6;
  const int q    = lane >> 4;
  const int m    = lane & 15;

  // ---- phase 0: stage (row-major: coalesced global reads) ----
  for (int idx = tid; idx < 64 * 78; idx += 256) {
    int r = idx / 78, c = idx % 78;
    int gy = by - 10 + r, gx = bx - 7 + c;
    float v = 0.f;
    if ((unsigned)gy < HH && (unsigned)gx < WW) v = ub[gy * WW + gx];
    suT[c * 72 + r] = f2bf(v);
  }
  for (int idx = tid; idx < 36 * 70; idx += 256) {
    int i = idx / 70, j = idx % 70;
    int gy = by - 2 + i, gx = bx - 2 + j;
    float v = 0.f;
    if ((unsigned)gy < HH && (unsigned)gx < WW) v = ib[gy * WW + gx];
    si[i * 70 + j] = v;
  }
  __syncthreads();

  // ---- phase 1a: edges on 34 rows x 66 cols (strips of 4) ----
  // edge pixel (by-1+i, bx-1+j), j<66; si window local (i+p, j+qq).
  for (int idx = tid; idx < 34 * 17; idx += 256) {
    int i = idx / 17, j0 = (idx % 17) * 4;
    float acc[8][4];
    #pragma unroll
    for (int c = 0; c < 8; ++c)
      #pragma unroll
      for (int t = 0; t < 4; ++t) acc[c][t] = 0.f;
    #pragma unroll
    for (int p = 0; p < 3; ++p) {
      float r[6];
      #pragma unroll
      for (int t = 0; t < 6; ++t) r[t] = si[(i + p) * 70 + j0 + t];
      #pragma unroll
      for (int qq = 0; qq < 3; ++qq) {
        float4 w0 = *reinterpret_cast<const float4*>(&ws[(p * 3 + qq) * 8]);
        float4 w1 = *reinterpret_cast<const float4*>(&ws[(p * 3 + qq) * 8 + 4]);
        #pragma unroll
        for (int t = 0; t < 4; ++t) {
          float v = r[qq + t];
          acc[0][t] = fmaf(v, w0.x, acc[0][t]);
          acc[1][t] = fmaf(v, w0.y, acc[1][t]);
          acc[2][t] = fmaf(v, w0.z, acc[2][t]);
          acc[3][t] = fmaf(v, w0.w, acc[3][t]);
          acc[4][t] = fmaf(v, w1.x, acc[4][t]);
          acc[5][t] = fmaf(v, w1.y, acc[5][t]);
          acc[6][t] = fmaf(v, w1.z, acc[6][t]);
          acc[7][t] = fmaf(v, w1.w, acc[7][t]);
        }
      }
    }
    int gy = by - 1 + i;
    #pragma unroll
    for (int t = 0; t < 4; ++t) {
      int j = j0 + t;
      if (j < 66) {
        int gx = bx - 1 + j;
        float val = 0.f;
        if ((unsigned)gy < HH && (unsigned)gx < WW) {
          float e = 0.f;
          #pragma unroll
          for (int c = 0; c < 8; ++c) e += fmaxf(acc[c][t], 0.f);
          val = e / (1.f + e);
        }
        sebf[i * 68 + j] = f2bf(val);
      }
    }
  }

  // ---- phase 1b: kappa via Toeplitz MFMA, 3x5=15 subtiles -> skp 36x68 ----
  {
    const unsigned short* KT = ((const unsigned short*)ws) + KT0 * 2;
    for (int s = wv; s < 15; s += 4) {
      int sty = s / 5, stx = s % 5;
      float4v acc = {0.f, 0.f, 0.f, 0.f};
      #pragma unroll
      for (int bb = 0; bb < 11; ++bb) {
        short8 af = *reinterpret_cast<const short8*>(KT + (bb * 64 + lane) * 8);
        // B[k][n] = u[by-2+sty*16+k-8][bx-2+stx*16+n+bb-5]
        //   suT local: col = stx*16+m+bb (<=89, in-bounds), row = sty*16+q*8..
        short8 bf = *reinterpret_cast<const short8*>(
            &suT[(stx * 16 + m + bb) * 72 + sty * 16 + q * 8]);
        acc = __builtin_amdgcn_mfma_f32_16x16x32_bf16(af, bf, acc, 0, 0, 0);
      }
      #pragma unroll
      for (int i = 0; i < 4; ++i) {
        int rl = sty * 16 + q * 4 + i, cl = stx * 16 + m;
        if (rl < 36 && cl < 68) {
          int yy = by - 2 + rl, xx = bx - 2 + cl;
          float v = 0.f;
          if ((unsigned)yy < HH && (unsigned)xx < WW)
            v = acc[i] * kk[(size_t)yy * WW + xx];
          skp[rl * 69 + cl] = v;
        }
      }
    }
  }
  __syncthreads();

  // ---- phase 2: grads via transposed MFMA + inline combine ----
  {
    short8 afr[4];
    const unsigned short* F = ((const unsigned short*)ws) + F0 * 2;
    #pragma unroll
    for (int t = 0; t < 4; ++t)
      afr[t] = *reinterpret_cast<const short8*>(F + (t * 64 + lane) * 8);

    #pragma unroll
    for (int h = 0; h < TX; h += 16) {
      const int cl = h + m;                 // pixel col (tile-local, 0..63)
      unsigned short W[9];
      #pragma unroll
      for (int d = 0; d < 3; ++d) {
        const unsigned short* rp = &sebf[(wv * 8 + d) * 68 + cl];
        W[3 * d + 0] = rp[0]; W[3 * d + 1] = rp[1]; W[3 * d + 2] = rp[2];
      }

      float rxv[8], ryv[8];
      #pragma unroll
      for (int r = 0; r < 8; ++r) {
        short8 bv = (short8)0;
        if (q == 0) {
          #pragma unroll
          for (int j = 0; j < 8; ++j) bv[j] = (short)W[j];
        } else if (q == 1) {
          bv[0] = (short)W[8];
        }

        float4v c0 = {0.f, 0.f, 0.f, 0.f}, c1 = c0, c2 = c0, c3 = c0;
        c0 = __builtin_amdgcn_mfma_f32_16x16x32_bf16(afr[0], bv, c0, 0, 0, 0);
        c1 = __builtin_amdgcn_mfma_f32_16x16x32_bf16(afr[1], bv, c1, 0, 0, 0);
        c2 = __builtin_amdgcn_mfma_f32_16x16x32_bf16(afr[2], bv, c2, 0, 0, 0);
        c3 = __builtin_amdgcn_mfma_f32_16x16x32_bf16(afr[3], bv, c3, 0, 0, 0);

        float rx = 0.f, ry = 0.f;
        #pragma unroll
        for (int i = 0; i < 4; ++i) {
          rx += fmaxf(c0[i], 0.f) + fmaxf(c1[i], 0.f);
          ry += fmaxf(c2[i], 0.f) + fmaxf(c3[i], 0.f);
        }
        rx += __shfl_xor(rx, 16); rx += __shfl_xor(rx, 32);
        ry += __shfl_xor(ry, 16); ry += __shfl_xor(ry, 32);
        rxv[r] = rx; ryv[r] = ry;

        if (r < 7) {
          #pragma unroll
          for (int t = 0; t < 6; ++t) W[t] = W[t + 3];
          const unsigned short* rp = &sebf[(wv * 8 + r + 3) * 68 + cl];
          W[6] = rp[0]; W[7] = rp[1]; W[8] = rp[2];
        }
      }

      // inline combine: lane (q,m) -> pixels (wv*8 + 2q + s, h + m), s=0,1
      {
        const int row0 = wv * 8 + 2 * q;       // tile-local pixel row base
        const int gx = bx + cl;
        float sk6[6][5];                        // 6 rows x 5 cols smoother window
        #pragma unroll
        for (int rr = 0; rr < 6; ++rr)
          #pragma unroll
          for (int n = 0; n < 5; ++n)
            sk6[rr][n] = skp[(row0 + rr) * 69 + cl + n];

        #pragma unroll
        for (int s = 0; s < 2; ++s) {
          int oy = row0 + s;
          int gy = by + oy;
          float kap = 0.f;
          #pragma unroll
          for (int m5 = 0; m5 < 5; ++m5)
            #pragma unroll
            for (int n = 0; n < 5; ++n)
              kap = fmaf(sk6[s + m5][n], sm[m5 * 5 + n], kap);

          float ec = bf2f(sebf[(oy + 1) * 68 + cl + 1]);
          const float* ur = ub + (size_t)gy * WW + gx;
          float uc = ur[0];
          float ul = gx > 0 ? ur[-1] : 0.f;
          float ud = gy < HH - 1 ? ur[WW] : 0.f;
          float xp = uc - ul;
          float yp = uc - ud;
          out[((size_t)b * HH + gy) * WW + gx] =
              uc + rxv[2 * q + s] * xp + ryv[2 * q + s] * yp + ec + kap;
        }
      }
    }
  }
}

// ---------------- Fallback: R3 monolith (used if ws too small) --------------
__global__ __launch_bounds__(256) void forcing_main(
    const float* __restrict__ u, const float* __restrict__ img,
    const float* __restrict__ kx, const float* __restrict__ ky,
    const float* __restrict__ sm, const float* __restrict__ kk,
    const float* __restrict__ ws, float* __restrict__ out) {
  __shared__ float su[46][48];
  __shared__ float si[36][37];
  __shared__ float se[34][35];
  __shared__ float sk[36][37];
  __shared__ float w_edge[72];
  __shared__ float w_kx[288];
  __shared__ float w_ky[288];
  __shared__ float w_k11[124];
  __shared__ float w_sm[28];

  const int bx = blockIdx.x * 32;
  const int by = blockIdx.y * 32;
  const int b  = blockIdx.z;
  const int tid = threadIdx.x;
  const float* ub = u   + (size_t)b * HH * WW;
  const float* ib = img + (size_t)b * HH * WW;

  for (int i = tid; i < 72; i += 256)  w_edge[i] = ws[i];
  for (int i = tid; i < 121; i += 256) w_k11[i]  = ws[72 + i];
  for (int i = tid; i < 288; i += 256) { w_kx[i] = kx[i]; w_ky[i] = ky[i]; }
  if (tid < 25) w_sm[tid] = sm[tid];

  for (int idx = tid; idx < 46 * 46; idx += 256) {
    int i = idx / 46, j = idx % 46;
    int gy = by - 7 + i, gx = bx - 7 + j;
    float v = 0.f;
    if ((unsigned)gy < HH && (unsigned)gx < WW) v = ub[gy * WW + gx];
    su[i][j] = v;
  }
  for (int idx = tid; idx < 36 * 36; idx += 256) {
    int i = idx / 36, j = idx % 36;
    int gy = by - 2 + i, gx = bx - 2 + j;
    float v = 0.f;
    if ((unsigned)gy < HH && (unsigned)gx < WW) v = ib[gy * WW + gx];
    si[i][j] = v;
  }
  __syncthreads();

  for (int idx = tid; idx < 34 * 9; idx += 256) {
    int i = idx / 9, j0 = (idx % 9) * 4;
    float acc[8][4];
    #pragma unroll
    for (int c = 0; c < 8; ++c)
      #pragma unroll
      for (int t = 0; t < 4; ++t) acc[c][t] = 0.f;
    #pragma unroll
    for (int p = 0; p < 3; ++p) {
      float r[6];
      #pragma unroll
      for (int t = 0; t < 6; ++t) r[t] = si[i + p][j0 + t];
      #pragma unroll
      for (int q = 0; q < 3; ++q) {
        const float4 w0 = *reinterpret_cast<const float4*>(&w_edge[(p * 3 + q) * 8]);
        const float4 w1 = *reinterpret_cast<const float4*>(&w_edge[(p * 3 + q) * 8 + 4]);
        #pragma unroll
        for (int t = 0; t < 4; ++t) {
          float v = r[q + t];
          acc[0][t] = fmaf(v, w0.x, acc[0][t]);
          acc[1][t] = fmaf(v, w0.y, acc[1][t]);
          acc[2][t] = fmaf(v, w0.z, acc[2][t]);
          acc[3][t] = fmaf(v, w0.w, acc[3][t]);
          acc[4][t] = fmaf(v, w1.x, acc[4][t]);
          acc[5][t] = fmaf(v, w1.y, acc[5][t]);
          acc[6][t] = fmaf(v, w1.z, acc[6][t]);
          acc[7][t] = fmaf(v, w1.w, acc[7][t]);
        }
      }
    }
    int gy = by - 1 + i;
    #pragma unroll
    for (int t = 0; t < 4; ++t) {
      int j = j0 + t;
      if (j < 34) {
        int gx = bx - 1 + j;
        float val = 0.f;
        if ((unsigned)gy < HH && (unsigned)gx < WW) {
          float e = 0.f;
          #pragma unroll
          for (int c = 0; c < 8; ++c) e += fmaxf(acc[c][t], 0.f);
          val = e / (1.f + e);
        }
        se[i][j] = val;
      }
    }
  }

  for (int idx = tid; idx < 36 * 9; idx += 256) {
    int i = idx / 9, js = (idx % 9) * 4;
    float o0 = 0.f, o1 = 0.f, o2 = 0.f, o3 = 0.f;
    #pragma unroll
    for (int A = 0; A < 11; ++A) {
      const float* row = &su[i + A][js];
      float4 v0 = *reinterpret_cast<const float4*>(row);
      float4 v1 = *reinterpret_cast<const float4*>(row + 4);
      float4 v2 = *reinterpret_cast<const float4*>(row + 8);
      float r[14] = {v0.x, v0.y, v0.z, v0.w, v1.x, v1.y, v1.z, v1.w,
                     v2.x, v2.y, v2.z, v2.w, row[12], row[13]};
      #pragma unroll
      for (int B2 = 0; B2 < 11; ++B2) {
        float w = w_k11[A * 11 + B2];
        o0 = fmaf(r[B2],     w, o0);
        o1 = fmaf(r[B2 + 1], w, o1);
        o2 = fmaf(r[B2 + 2], w, o2);
        o3 = fmaf(r[B2 + 3], w, o3);
      }
    }
    int gy = by - 2 + i;
    float o[4] = {o0, o1, o2, o3};
    #pragma unroll
    for (int t = 0; t < 4; ++t) {
      int gx = bx - 2 + js + t;
      float val = 0.f;
      if ((unsigned)gy < HH && (unsigned)gx < WW) val = o[t] * kk[gy * WW + gx];
      sk[i][js + t] = val;
    }
  }
  __syncthreads();

  {
    const int oy = tid >> 3;
    const int ox = (tid & 7) * 4;
    const int gy = by + oy;
    const int gx = bx + ox;

    float e[3][6];
    #pragma unroll
    for (int p = 0; p < 3; ++p)
      #pragma unroll
      for (int t = 0; t < 6; ++t) e[p][t] = se[oy + p][ox + t];

    const float4* wx4 = reinterpret_cast<const float4*>(w_kx);
    const float4* wy4 = reinterpret_cast<const float4*>(w_ky);

    float gxa[4] = {0.f, 0.f, 0.f, 0.f};
    float gya[4] = {0.f, 0.f, 0.f, 0.f};
    #pragma unroll
    for (int cq = 0; cq < 8; ++cq) {
      float sx[4][4], sy[4][4];
      #pragma unroll
      for (int cc = 0; cc < 4; ++cc)
        #pragma unroll
        for (int t = 0; t < 4; ++t) { sx[cc][t] = 0.f; sy[cc][t] = 0.f; }
      #pragma unroll
      for (int p = 0; p < 3; ++p)
        #pragma unroll
        for (int q = 0; q < 3; ++q) {
          float4 wx = wx4[(p * 3 + q) * 8 + cq];
          float4 wy = wy4[(p * 3 + q) * 8 + cq];
          #pragma unroll
          for (int t = 0; t < 4; ++t) {
            float evv = e[p][q + t];
            sx[0][t] = fmaf(evv, wx.x, sx[0][t]);
            sx[1][t] = fmaf(evv, wx.y, sx[1][t]);
            sx[2][t] = fmaf(evv, wx.z, sx[2][t]);
            sx[3][t] = fmaf(evv, wx.w, sx[3][t]);
            sy[0][t] = fmaf(evv, wy.x, sy[0][t]);
            sy[1][t] = fmaf(evv, wy.y, sy[1][t]);
            sy[2][t] = fmaf(evv, wy.z, sy[2][t]);
            sy[3][t] = fmaf(evv, wy.w, sy[3][t]);
          }
        }
      #pragma unroll
      for (int cc = 0; cc < 4; ++cc)
        #pragma unroll
        for (int t = 0; t < 4; ++t) {
          gxa[t] += fmaxf(sx[cc][t], 0.f);
          gya[t] += fmaxf(sy[cc][t], 0.f);
        }
    }

    float res[4];
    #pragma unroll
    for (int t = 0; t < 4; ++t) {
      float kap = 0.f;
      #pragma unroll
      for (int m = 0; m < 5; ++m)
        #pragma unroll
        for (int n = 0; n < 5; ++n)
          kap = fmaf(sk[oy + m][ox + t + n], w_sm[m * 5 + n], kap);

      float uc = su[oy + 7][ox + 7 + t];
      float xp = uc - su[oy + 7][ox + 6 + t];
      float yp = uc - su[oy + 8][ox + 7 + t];
      float ec = se[oy + 1][ox + 1 + t];
      res[t] = uc + gxa[t] * xp + gya[t] * yp + ec + kap;
    }

    float4 r4 = make_float4(res[0], res[1], res[2], res[3]);
    *reinterpret_cast<float4*>(&out[((size_t)b * HH + gy) * WW + gx]) = r4;
  }
}

extern "C" void kernel_launch(void* const* d_in, const int* in_sizes, int n_in,
                              void* d_out, int out_size, void* d_ws, size_t ws_size,
                              hipStream_t stream) {
  const float* u   = (const float*)d_in[0];
  const float* img = (const float*)d_in[1];
  const float* kx  = (const float*)d_in[2];
  const float* ky  = (const float*)d_in[3];
  const float* kd  = (const float*)d_in[4];
  const float* kp  = (const float*)d_in[5];
  const float* k0  = (const float*)d_in[6];
  const float* k1  = (const float*)d_in[7];
  const float* k2  = (const float*)d_in[8];
  const float* sm  = (const float*)d_in[9];
  const float* kk  = (const float*)d_in[10];
  float* out = (float*)d_out;
  float* ws  = (float*)d_ws;

  precompute_kernels<<<1, 256, 0, stream>>>(kd, kp, k0, k1, k2, kx, ky, ws);
  if (ws != nullptr && ws_size >= WS_NEEDED_BYTES) {
    dim3 grid(WW / TX, HH / TY, BB);
    fused<<<grid, 256, 0, stream>>>(u, img, kk, sm, ws, out);
  } else {
    dim3 grid(WW / 32, HH / 32, BB);
    forcing_main<<<grid, 256, 0, stream>>>(u, img, kx, ky, sm, kk, ws, out);
  }
}